// Round 18
// baseline (32.921 us; speedup 1.0000x reference)
//
#include <hip/hip_runtime.h>
#include <hip/hip_bf16.h>

typedef __bf16 bf16x8 __attribute__((ext_vector_type(8)));
typedef float  f32x4  __attribute__((ext_vector_type(4)));

#define IN_DIM 256
#define OUT_DIM 32
#define NCLS 50
#define INV_T (1.0f / 0.6f)
#define OSTRIDE (NCLS * OUT_DIM)   // 1600

__device__ __forceinline__ void gload_lds16(const void* g, void* l) {
    __builtin_amdgcn_global_load_lds(
        (const __attribute__((address_space(1))) void*)g,
        (__attribute__((address_space(3))) void*)l, 16, 0, 0);
}

// prep_w: 50 blocks; W'[c,o,i] = bf16(W[c,o,i] * exp((gamma_i - max gamma)/T))
__global__ __launch_bounds__(256) void prep_w(const float* __restrict__ w,
                                              __bf16* __restrict__ wb) {
    __shared__ float wm[4];
    int c = blockIdx.x;
    int i = threadIdx.x;
    const float* wc = w + (size_t)c * OUT_DIM * IN_DIM + i;
    float wv[OUT_DIM];
#pragma unroll
    for (int o = 0; o < OUT_DIM; ++o) wv[o] = wc[o * IN_DIM];
    float gsum = 0.f;
#pragma unroll
    for (int o = 0; o < OUT_DIM; ++o) gsum += fabsf(wv[o]);
    float m = gsum;
#pragma unroll
    for (int s = 1; s < 64; s <<= 1) m = fmaxf(m, __shfl_xor(m, s));
    if ((threadIdx.x & 63) == 0) wm[threadIdx.x >> 6] = m;
    __syncthreads();
    m = fmaxf(fmaxf(wm[0], wm[1]), fmaxf(wm[2], wm[3]));
    float an = __expf((gsum - m) * INV_T);
    __bf16* wo = wb + (size_t)c * OUT_DIM * IN_DIM + i;
#pragma unroll
    for (int o = 0; o < OUT_DIM; ++o)
        wo[o * IN_DIM] = (__bf16)(wv[o] * an);
}

// GEMM: out[b,c,o] = sum_i x[b,i]*W'[c,o,i] + bias[c,o]
// Grid 256 (1 block/CU), block = 512 threads = 8 waves. Block owns 32 rows
// for ALL 50 classes. Wave octant: rg = w&1 (16-row group), oh = (w>>1)&1
// (o-half), cpar = w>>2 (class parity). A (x rows) converted f32->bf16 into
// 32 pinned VGPRs once. W' ring: 8 slots x 16KB (class c -> slot c&7),
// staged contiguous via global_load_lds, stage-ahead 3 rounds, stage AFTER
// the barrier => live slots {2r..2r+7} mod 8 all distinct (race-free).
// Round r: VMW -> s_barrier -> stage classes 2r+6,2r+7 -> compute class
// 2r+cpar (8 ds_read W + 8 MFMA) -> store (row-sequential 64-float steps).
// Own-wave vmcnt (4 stage loads + 1 store per round):
//   r<=22: VMW(11) = S(r-3)+4+S(r-2)+4+S(r-1); r==23: 7; r==24: 3.
// LDS swizzle (both-sides): phys 16B-slot s of W-row rr holds s^(rr&15).
__global__ __launch_bounds__(512, 2) void gemm(const float* __restrict__ x,
                                               const __bf16* __restrict__ wb,
                                               const float* __restrict__ bias,
                                               float* __restrict__ out) {
    __shared__ __align__(16) char lds[8 * 16384 + 6400];  // W ring + bias
    float* bias_lds = (float*)(lds + 8 * 16384);

    int bid = blockIdx.x;
    int row0 = bid * 32;
    int tid = threadIdx.x;
    int lane = tid & 63;
    int w8 = tid >> 6;           // 0..7
    int rg = w8 & 1;
    int oh = (w8 >> 1) & 1;
    int cpar = w8 >> 2;
    int l15 = lane & 15;
    int g = lane >> 4;
    int s31 = lane & 31;
    int lr = lane >> 5;

    // --- A: 16 rows x 256 K, f32 -> bf16, register-resident ---
    const float* xrow = x + (size_t)(row0 + rg * 16 + l15) * IN_DIM + g * 8;
    bf16x8 A[8];
#pragma unroll
    for (int kk = 0; kk < 8; ++kk) {
        f32x4 lo = *reinterpret_cast<const f32x4*>(xrow + kk * 32);
        f32x4 hi = *reinterpret_cast<const f32x4*>(xrow + kk * 32 + 4);
        bf16x8 a;
        a[0] = (__bf16)lo[0]; a[1] = (__bf16)lo[1]; a[2] = (__bf16)lo[2]; a[3] = (__bf16)lo[3];
        a[4] = (__bf16)hi[0]; a[5] = (__bf16)hi[1]; a[6] = (__bf16)hi[2]; a[7] = (__bf16)hi[3];
        A[kk] = a;
    }

    // --- prologue: stage classes 0..5 (slots 0..5, 192 rows, 24/wave) ---
    const char* wsrc = (const char*)wb;
#pragma unroll
    for (int j = 0; j < 12; ++j) {
        int re = w8 * 24 + 2 * j;
        int rr = re + lr;
        gload_lds16(wsrc + (size_t)rr * 512 + ((s31 ^ (rr & 15)) * 16),
                    lds + re * 512);
    }
    // bias -> LDS (400 f32x4)
    if (tid < 400) {
        f32x4 b = *reinterpret_cast<const f32x4*>(bias + tid * 4);
        *reinterpret_cast<f32x4*>(bias_lds + tid * 4) = b;
    }
    // pin A (forces x-loads complete; stage/bias may stay in flight)
#pragma unroll
    for (int kk = 0; kk < 8; ++kk)
        asm volatile("" : "+v"(A[kk]));
    __syncthreads();   // full drain: slots 0..5 + bias visible, vmcnt=0

    float* outp = out + (size_t)(row0 + rg * 16 + l15) * OSTRIDE
                      + cpar * OUT_DIM + oh * 16 + g * 4;

#define VMW(N) asm volatile("s_waitcnt vmcnt(" #N ")" ::: "memory")
#pragma unroll
    for (int r = 0; r < 25; ++r) {
        if (r <= 22)      VMW(11);
        else if (r == 23) VMW(7);
        else              VMW(3);
        __builtin_amdgcn_sched_barrier(0);
        __builtin_amdgcn_s_barrier();
        __builtin_amdgcn_sched_barrier(0);

        if (r <= 21) {
            int cb = 2 * r + 6;                  // stage classes cb, cb+1
#pragma unroll
            for (int j = 0; j < 4; ++j) {
                int re = w8 * 8 + 2 * j;         // 0..63 across 8 waves
                int rr = re + lr;
                gload_lds16(wsrc + ((size_t)cb * 32 + rr) * 512 + ((s31 ^ (rr & 15)) * 16),
                            lds + ((cb & 7) * 32 + re) * 512);
            }
        }

        int c = 2 * r + cpar;
        const char* slot = lds + (size_t)(c & 7) * 16384;
        f32x4 acc = *reinterpret_cast<const f32x4*>(bias_lds + c * 32 + oh * 16 + g * 4);
#pragma unroll
        for (int kk = 0; kk < 8; ++kk) {
            bf16x8 Wf = *reinterpret_cast<const bf16x8*>(
                slot + (size_t)(oh * 16 + l15) * 512 + (((4 * kk + g) ^ l15) * 16));
            acc = __builtin_amdgcn_mfma_f32_16x16x32_bf16(Wf, A[kk], acc, 0, 0, 0);
        }
        *reinterpret_cast<f32x4*>(outp) = acc;
        outp += 64;                              // 2 classes = 64 floats/round
    }
#undef VMW
}

extern "C" void kernel_launch(void* const* d_in, const int* in_sizes, int n_in,
                              void* d_out, int out_size, void* d_ws, size_t ws_size,
                              hipStream_t stream) {
    const float* x    = (const float*)d_in[0];
    const float* w    = (const float*)d_in[1];
    const float* bias = (const float*)d_in[2];
    float* out = (float*)d_out;

    __bf16* wb = (__bf16*)d_ws;                  // 50*32*256 bf16 = 0.8 MB

    prep_w<<<NCLS, 256, 0, stream>>>(w, wb);
    gemm<<<256, 512, 0, stream>>>(x, wb, bias, out);
}

// Round 19
// 28.341 us; speedup vs baseline: 1.1616x; 1.1616x over previous
//
#include <hip/hip_runtime.h>
#include <hip/hip_bf16.h>

typedef __bf16 bf16x8 __attribute__((ext_vector_type(8)));
typedef float  f32x4  __attribute__((ext_vector_type(4)));

#define B_ROWS 8192
#define IN_DIM 256
#define OUT_DIM 32
#define NCLS 50
#define INV_T (1.0f / 0.6f)

#define CVT_BLOCKS 1024  // x cvt: 8192*256 / (256*8)
#define ROWTILES 16      // 8192 / 512 rows per block
#define NCHUNK 8         // 128 rows/wave / 16

__device__ __forceinline__ void gload_lds16(const void* g, void* l) {
    __builtin_amdgcn_global_load_lds(
        (const __attribute__((address_space(1))) void*)g,
        (__attribute__((address_space(3))) void*)l, 16, 0, 0);
}

// prep (single launch): blocks [0,50) = W-class blocks (first, so they
// overlap under the cvt blocks); blocks [50,1074) convert x f32->bf16.
// W-block: single pass — 32 w-values in regs, gamma/alpha, write W'.
__global__ __launch_bounds__(256) void prep(const float* __restrict__ x,
                                            const float* __restrict__ w,
                                            __bf16* __restrict__ xb,
                                            __bf16* __restrict__ wb) {
    __shared__ float wm[4];
    int bid = blockIdx.x;
    if (bid < NCLS) {
        int c = bid;
        int i = threadIdx.x;  // IN index
        const float* wc = w + (size_t)c * OUT_DIM * IN_DIM + i;
        float wv[OUT_DIM];
#pragma unroll
        for (int o = 0; o < OUT_DIM; ++o) wv[o] = wc[o * IN_DIM];
        float gsum = 0.f;
#pragma unroll
        for (int o = 0; o < OUT_DIM; ++o) gsum += fabsf(wv[o]);
        float m = gsum;
#pragma unroll
        for (int s = 1; s < 64; s <<= 1) m = fmaxf(m, __shfl_xor(m, s));
        if ((threadIdx.x & 63) == 0) wm[threadIdx.x >> 6] = m;
        __syncthreads();
        m = fmaxf(fmaxf(wm[0], wm[1]), fmaxf(wm[2], wm[3]));
        float an = __expf((gsum - m) * INV_T);
        __bf16* wo = wb + (size_t)c * OUT_DIM * IN_DIM + i;
#pragma unroll
        for (int o = 0; o < OUT_DIM; ++o)
            wo[o * IN_DIM] = (__bf16)(wv[o] * an);
    } else {
        int i = ((bid - NCLS) * 256 + threadIdx.x) * 8;
        float4 v0 = *reinterpret_cast<const float4*>(x + i);
        float4 v1 = *reinterpret_cast<const float4*>(x + i + 4);
        bf16x8 r;
        r[0] = (__bf16)v0.x; r[1] = (__bf16)v0.y; r[2] = (__bf16)v0.z; r[3] = (__bf16)v0.w;
        r[4] = (__bf16)v1.x; r[5] = (__bf16)v1.y; r[6] = (__bf16)v1.z; r[7] = (__bf16)v1.w;
        *reinterpret_cast<bf16x8*>(xb + i) = r;
    }
}

// GEMM (r9/r14 structure — proven best, 28.2us total):
// out[b, c, o] = sum_i xb[b,i]*wb[c,o,i] + bias[c,o]
// grid = 25 class-PAIRS * 16 row-tiles; block = 4 waves, 512 rows, 2 classes.
// W' slab (32 KB, 64 rows) staged into the union of the 4 waves' Abuf1
// regions (disjoint from Abuf0/chunk0): row r -> lds + (r>>4)*16384 + 8192
// + (r&15)*512. Read into 128 pinned VGPRs, then chunk pipeline.
// Counted vmcnt: 12 = 8 next-chunk loads + 4 stores (in-order decrement).
// LDS swizzle (both-sides): phys 16B-slot s of row r holds logical s^(r&15).
__global__ __launch_bounds__(256, 2) void gemm(const __bf16* __restrict__ xb,
                                               const __bf16* __restrict__ wb,
                                               const float* __restrict__ bias,
                                               float* __restrict__ out) {
    __shared__ __align__(16) char lds[4 * 2 * 8192];  // 4 waves * {Abuf0, Abuf1}

    int bid = blockIdx.x;
    int cp = bid >> 4;           // 0..24
    int rt = bid & (ROWTILES - 1);
    int c0 = cp * 2;
    int row0 = rt * 512;
    int lane = threadIdx.x & 63;
    int w4 = threadIdx.x >> 6;
    int l15 = lane & 15;
    int g = lane >> 4;
    int s31 = lane & 31;
    int lr = lane >> 5;          // 0/1

    char* Abuf0 = lds + w4 * 16384;
    char* Abuf1 = Abuf0 + 8192;

    // --- stage A chunk 0 (wave-private 16 rows = 8 KB) into Abuf0 ---
    const char* arows = (const char*)(xb + (size_t)(row0 + w4 * 128) * IN_DIM);
#define STAGE_A(BUF, CHUNK)                                                       \
    _Pragma("unroll") for (int il = 0; il < 8; ++il) {                            \
        int r = (CHUNK) * 16 + 2 * il + lr;                                       \
        gload_lds16(arows + (size_t)r * 512 + ((s31 ^ (r & 15)) * 16),            \
                    (BUF) + il * 1024);                                           \
    }
    STAGE_A(Abuf0, 0)

    // --- stage W' pair (32 KB = 64 rows) into the Abuf1 regions ---
    const char* wsrc = (const char*)(wb + (size_t)c0 * OUT_DIM * IN_DIM);
#pragma unroll
    for (int jw = 0; jw < 8; ++jw) {
        int re = jw * 8 + w4 * 2;              // even row of this instr
        int r = re + lr;
        gload_lds16(wsrc + (size_t)r * 512 + ((s31 ^ (r & 15)) * 16),
                    lds + (re >> 4) * 16384 + 8192 + (re & 15) * 512);
    }

    asm volatile("s_waitcnt vmcnt(0)" ::: "memory");
    __syncthreads();
    __builtin_amdgcn_sched_barrier(0);

    // --- W' -> regs (swizzled ds_read); W row = ci*32 + l15 (+16) ---
    bf16x8 W[2][16];
#pragma unroll
    for (int ci = 0; ci < 2; ++ci)
#pragma unroll
        for (int kk = 0; kk < 8; ++kk) {
            int slot = (4 * kk + g) ^ l15;
            W[ci][kk]     = *reinterpret_cast<const bf16x8*>(
                lds + (2 * ci) * 16384 + 8192 + l15 * 512 + slot * 16);
            W[ci][8 + kk] = *reinterpret_cast<const bf16x8*>(
                lds + (2 * ci + 1) * 16384 + 8192 + l15 * 512 + slot * 16);
        }
#pragma unroll
    for (int ci = 0; ci < 2; ++ci)
#pragma unroll
        for (int kk = 0; kk < 16; ++kk)
            asm volatile("" : "+v"(W[ci][kk]));
    __builtin_amdgcn_sched_barrier(0);
    __syncthreads();   // all waves done reading W before chunk 1 stages Abuf1

    f32x4 bv00 = *reinterpret_cast<const f32x4*>(bias + c0 * OUT_DIM + g * 4);
    f32x4 bv01 = *reinterpret_cast<const f32x4*>(bias + c0 * OUT_DIM + 16 + g * 4);
    f32x4 bv10 = *reinterpret_cast<const f32x4*>(bias + (c0 + 1) * OUT_DIM + g * 4);
    f32x4 bv11 = *reinterpret_cast<const f32x4*>(bias + (c0 + 1) * OUT_DIM + 16 + g * 4);

    float* orow = out + (size_t)(row0 + w4 * 128 + l15) * (NCLS * OUT_DIM) + c0 * OUT_DIM + g * 4;

    // --- main loop: 8 chunks of 16 rows, 2 classes each ---
#pragma unroll
    for (int k = 0; k < NCHUNK; ++k) {
        char* cur = (k & 1) ? Abuf1 : Abuf0;
        char* nxt = (k & 1) ? Abuf0 : Abuf1;
        if (k + 1 < NCHUNK) {
            STAGE_A(nxt, k + 1)
            asm volatile("s_waitcnt vmcnt(12)" ::: "memory");
        } else {
            asm volatile("s_waitcnt vmcnt(4)" ::: "memory");
        }
        __builtin_amdgcn_sched_barrier(0);

        f32x4 acc00 = bv00;
        f32x4 acc01 = bv01;
        f32x4 acc10 = bv10;
        f32x4 acc11 = bv11;
#pragma unroll
        for (int kk = 0; kk < 8; ++kk) {
            int slot = (4 * kk + g) ^ l15;
            bf16x8 a = *reinterpret_cast<const bf16x8*>(cur + (size_t)l15 * 512 + slot * 16);
            acc00 = __builtin_amdgcn_mfma_f32_16x16x32_bf16(W[0][kk],     a, acc00, 0, 0, 0);
            acc01 = __builtin_amdgcn_mfma_f32_16x16x32_bf16(W[0][8 + kk], a, acc01, 0, 0, 0);
            acc10 = __builtin_amdgcn_mfma_f32_16x16x32_bf16(W[1][kk],     a, acc10, 0, 0, 0);
            acc11 = __builtin_amdgcn_mfma_f32_16x16x32_bf16(W[1][8 + kk], a, acc11, 0, 0, 0);
        }
        float* op = orow + (size_t)k * 16 * (NCLS * OUT_DIM);
        *reinterpret_cast<f32x4*>(op) = acc00;
        *reinterpret_cast<f32x4*>(op + 16) = acc01;
        *reinterpret_cast<f32x4*>(op + OUT_DIM) = acc10;
        *reinterpret_cast<f32x4*>(op + OUT_DIM + 16) = acc11;
    }
#undef STAGE_A
}

extern "C" void kernel_launch(void* const* d_in, const int* in_sizes, int n_in,
                              void* d_out, int out_size, void* d_ws, size_t ws_size,
                              hipStream_t stream) {
    const float* x    = (const float*)d_in[0];
    const float* w    = (const float*)d_in[1];
    const float* bias = (const float*)d_in[2];
    float* out = (float*)d_out;

    __bf16* xb = (__bf16*)d_ws;                      // 8192*256 bf16 = 4 MB
    __bf16* wb = xb + (size_t)B_ROWS * IN_DIM;       // 50*32*256 bf16 = 0.8 MB

    prep<<<NCLS + CVT_BLOCKS, 256, 0, stream>>>(x, w, xb, wb);
    gemm<<<25 * ROWTILES, 256, 0, stream>>>(xb, wb, bias, out);
}